// Round 1
// baseline (570.296 us; speedup 1.0000x reference)
//
#include <hip/hip_runtime.h>
#include <hip/hip_bf16.h>
#include <cstdint>
#include <cstddef>

typedef __bf16 bf16_t;
typedef __bf16 bf16x8 __attribute__((ext_vector_type(8)));
typedef __bf16 bf16x4v __attribute__((ext_vector_type(4)));
typedef float f32x4 __attribute__((ext_vector_type(4)));

#define DEVI static __device__ __forceinline__

// async global->LDS, 16B per lane. LDS dest must be wave-uniform base + lane*16.
DEVI void gl_lds16(const void* g, void* l) {
    __builtin_amdgcn_global_load_lds((const __attribute__((address_space(1))) void*)g,
                                     (__attribute__((address_space(3))) void*)l, 16, 0, 0);
}

DEVI float rmax16(float v) {
    v = fmaxf(v, __shfl_xor(v, 1));
    v = fmaxf(v, __shfl_xor(v, 2));
    v = fmaxf(v, __shfl_xor(v, 4));
    v = fmaxf(v, __shfl_xor(v, 8));
    return v;
}
DEVI float rsum16(float v) {
    v += __shfl_xor(v, 1);
    v += __shfl_xor(v, 2);
    v += __shfl_xor(v, 4);
    v += __shfl_xor(v, 8);
    return v;
}

// ---------------- cast fp32 -> bf16 (vectorized) ----------------
__global__ __launch_bounds__(256) void castk(const float* __restrict__ in, bf16_t* __restrict__ out) {
    size_t i = ((size_t)blockIdx.x * 256 + threadIdx.x) * 4;
    float4 v = *(const float4*)(in + i);
    bf16x4v o;
    o[0] = (bf16_t)v.x; o[1] = (bf16_t)v.y; o[2] = (bf16_t)v.z; o[3] = (bf16_t)v.w;
    *(bf16x4v*)(out + i) = o;
}

// ---------------- transpose+cast weight 1024x1024: Wt[n][k] = W[k][n] ----------------
__global__ __launch_bounds__(256) void wtrans(const float* __restrict__ W0, const float* __restrict__ W1,
                                              const float* __restrict__ W2, const float* __restrict__ W3,
                                              bf16_t* __restrict__ O0, bf16_t* __restrict__ O1,
                                              bf16_t* __restrict__ O2, bf16_t* __restrict__ O3) {
    const float* W; bf16_t* O;
    switch (blockIdx.z) {
        case 0: W = W0; O = O0; break;
        case 1: W = W1; O = O1; break;
        case 2: W = W2; O = O2; break;
        default: W = W3; O = O3; break;
    }
    __shared__ float t[32][33];
    int tx = threadIdx.x & 31, ty = threadIdx.x >> 5;   // 32x8
    int bx = blockIdx.x * 32, by = blockIdx.y * 32;     // bx: n, by: k
#pragma unroll
    for (int yy = 0; yy < 4; ++yy)
        t[ty + yy * 8][tx] = W[(size_t)(by + ty + yy * 8) * 1024 + bx + tx];
    __syncthreads();
#pragma unroll
    for (int yy = 0; yy < 4; ++yy)
        O[(size_t)(bx + ty + yy * 8) * 1024 + by + tx] = (bf16_t)t[tx][ty + yy * 8];
}

// ---------------- RoPE tables: ctab/stab [2048][32] fp32 ----------------
__global__ __launch_bounds__(256) void rope_tab(float* __restrict__ ctab, float* __restrict__ stab) {
    int idx = blockIdx.x * 256 + threadIdx.x;   // 65536 = 2048*32
    int s = idx >> 5, i = idx & 31;
    float inv = 1.0f / powf(10000.0f, (float)i * (1.0f / 32.0f));
    float f = (float)s * inv;
    ctab[idx] = cosf(f);
    stab[idx] = sinf(f);
}

// ---------------- V transpose: V[b,h,s,d] -> Vt[b,h,d,s] ----------------
__global__ __launch_bounds__(256) void vtrans(const bf16_t* __restrict__ V, bf16_t* __restrict__ Vt) {
    const int bh = blockIdx.y, s0 = blockIdx.x * 64;
    __shared__ bf16_t t[64][72];
    int tid = threadIdx.x;
    int row = tid >> 2, col = (tid & 3) * 16;
    const bf16_t* src = V + ((size_t)bh * 2048 + s0 + row) * 64 + col;
    bf16x8 a0 = *(const bf16x8*)(src);
    bf16x8 a1 = *(const bf16x8*)(src + 8);
#pragma unroll
    for (int k = 0; k < 8; ++k) { t[row][col + k] = a0[k]; t[row][col + 8 + k] = a1[k]; }
    __syncthreads();
    int d = tid >> 2, sc = (tid & 3) * 16;
    bf16x8 b0, b1;
#pragma unroll
    for (int k = 0; k < 8; ++k) { b0[k] = t[sc + k][d]; b1[k] = t[sc + 8 + k][d]; }
    bf16_t* dst = Vt + ((size_t)bh * 64 + d) * 2048 + s0 + sc;
    *(bf16x8*)dst = b0;
    *(bf16x8*)(dst + 8) = b1;
}

// ---------------- GEMM: C[8192,1024] = A[8192,1024] x Bt[1024,1024]^T ----------------
// MODE 0: bf16 store to [b,h,s,d] with RoPE + scale (Q/K)
// MODE 1: bf16 store to [b,h,s,d] plain (V)
// MODE 2: fp32 store to [m,n] + bias (final out)
template <int MODE>
__global__ __launch_bounds__(256) void gemm_bt(const bf16_t* __restrict__ A, const bf16_t* __restrict__ Bt,
                                               const float* __restrict__ bias, void* __restrict__ Cout,
                                               const float* __restrict__ ctab, const float* __restrict__ stab,
                                               float scale) {
    constexpr int K = 1024, N = 1024;
    __shared__ alignas(16) bf16_t As[128 * 32];
    __shared__ alignas(16) bf16_t Bs[128 * 32];
    const int tid = threadIdx.x;
    const int w = tid >> 6, lane = tid & 63, c = lane & 15, qd = lane >> 4;
    const int wm = w >> 1, wn = w & 1;
    const int m0 = blockIdx.y * 128, n0 = blockIdx.x * 128;
    f32x4 acc[4][4] = {};
    for (int kt = 0; kt < K / 32; ++kt) {
#pragma unroll
        for (int l = 0; l < 2; ++l) {
            int e = (l * 256 + tid) * 8;
            int row = e >> 5, col = e & 31;
            gl_lds16(A + (size_t)(m0 + row) * K + kt * 32 + col, (char*)As + (size_t)e * 2);
            gl_lds16(Bt + (size_t)(n0 + row) * K + kt * 32 + col, (char*)Bs + (size_t)e * 2);
        }
        __syncthreads();
        bf16x8 af[4], bfr[4];
#pragma unroll
        for (int i = 0; i < 4; ++i) af[i] = *(const bf16x8*)&As[(wm * 64 + i * 16 + c) * 32 + qd * 8];
#pragma unroll
        for (int j = 0; j < 4; ++j) bfr[j] = *(const bf16x8*)&Bs[(wn * 64 + j * 16 + c) * 32 + qd * 8];
#pragma unroll
        for (int i = 0; i < 4; ++i)
#pragma unroll
            for (int j = 0; j < 4; ++j)
                acc[i][j] = __builtin_amdgcn_mfma_f32_16x16x32_bf16(af[i], bfr[j], acc[i][j], 0, 0, 0);
        __syncthreads();
    }
    const int mb = m0 + wm * 64;
    const int nb = n0 + wn * 64;   // head-aligned (64): nb>>6 = head for MODE 0/1
    if constexpr (MODE == 2) {
        float* O = (float*)Cout;
#pragma unroll
        for (int i = 0; i < 4; ++i)
#pragma unroll
            for (int j = 0; j < 4; ++j) {
                int n = nb + j * 16 + c;
                float bv = bias[n];
#pragma unroll
                for (int r = 0; r < 4; ++r) {
                    int m = mb + i * 16 + qd * 4 + r;
                    O[(size_t)m * N + n] = acc[i][j][r] + bv;
                }
            }
    } else if constexpr (MODE == 1) {
        bf16_t* O = (bf16_t*)Cout;
        int h = nb >> 6;
#pragma unroll
        for (int i = 0; i < 4; ++i)
#pragma unroll
            for (int j = 0; j < 4; ++j) {
                int d = j * 16 + c;
                float bv = bias[nb + d];
#pragma unroll
                for (int r = 0; r < 4; ++r) {
                    int m = mb + i * 16 + qd * 4 + r;
                    int b = m >> 11, s = m & 2047;
                    O[((size_t)(b * 16 + h) * 2048 + s) * 64 + d] = (bf16_t)(acc[i][j][r] + bv);
                }
            }
    } else {
        bf16_t* O = (bf16_t*)Cout;
        int h = nb >> 6;
#pragma unroll
        for (int i = 0; i < 4; ++i)
#pragma unroll
            for (int jh = 0; jh < 2; ++jh) {
                int d1 = jh * 16 + c;                 // [0,32)
                float b1 = bias[nb + d1];
                float b2 = bias[nb + d1 + 32];
#pragma unroll
                for (int r = 0; r < 4; ++r) {
                    int m = mb + i * 16 + qd * 4 + r;
                    int b = m >> 11, s = m & 2047;
                    float v1 = acc[i][jh][r] + b1;
                    float v2 = acc[i][jh + 2][r] + b2;
                    float ct = ctab[s * 32 + d1];
                    float st = stab[s * 32 + d1];
                    size_t base = ((size_t)(b * 16 + h) * 2048 + s) * 64;
                    O[base + d1]      = (bf16_t)((v1 * ct - v2 * st) * scale);
                    O[base + d1 + 32] = (bf16_t)((v2 * ct + v1 * st) * scale);
                }
            }
    }
}

// ---------------- flash attention: per block (b,h) x 128 q-rows ----------------
// Q pre-scaled by 1/8. Q,K: [b,h,s,64] bf16. Vt: [b,h,64,s] bf16. ctx out: [b,s,h*64+d] bf16.
__global__ __launch_bounds__(256) void attn(const bf16_t* __restrict__ Q, const bf16_t* __restrict__ K,
                                            const bf16_t* __restrict__ Vt, bf16_t* __restrict__ ctx) {
    constexpr int S = 2048;
    __shared__ alignas(16) bf16_t Qs[128 * 64];
    __shared__ alignas(16) bf16_t Ks[64 * 64];
    __shared__ alignas(16) bf16_t Vts[64 * 64];
    __shared__ alignas(16) bf16_t Ps[4][32 * 64];
    const int tid = threadIdx.x, w = tid >> 6, lane = tid & 63, c = lane & 15, qd = lane >> 4;
    const int bh = blockIdx.y, q0 = blockIdx.x * 128;
    const bf16_t* Qb = Q + (size_t)bh * S * 64 + (size_t)q0 * 64;
    const bf16_t* Kb = K + (size_t)bh * S * 64;
    const bf16_t* Vb = Vt + (size_t)bh * 64 * S;
#pragma unroll
    for (int l = 0; l < 4; ++l) {
        int e = (l * 256 + tid) * 8;
        gl_lds16(Qb + e, (char*)Qs + (size_t)e * 2);
    }
    f32x4 acc_o[2][4] = {};
    float m_st[2][4], l_st[2][4];
#pragma unroll
    for (int i = 0; i < 2; ++i)
#pragma unroll
        for (int r = 0; r < 4; ++r) { m_st[i][r] = -1e30f; l_st[i][r] = 0.f; }
    __syncthreads();
    for (int kt = 0; kt < S / 64; ++kt) {
        const int s0 = kt * 64;
#pragma unroll
        for (int l = 0; l < 2; ++l) {
            int e = (l * 256 + tid) * 8;
            gl_lds16(Kb + (size_t)s0 * 64 + e, (char*)Ks + (size_t)e * 2);
            int dr = e >> 6, sc = e & 63;
            gl_lds16(Vb + (size_t)dr * S + s0 + sc, (char*)Vts + (size_t)e * 2);
        }
        __syncthreads();
        // S_tile = Q . K^T   (scores pre-scaled via Q)
        f32x4 sc_[2][4];
#pragma unroll
        for (int i = 0; i < 2; ++i)
#pragma unroll
            for (int j = 0; j < 4; ++j) sc_[i][j] = f32x4{0.f, 0.f, 0.f, 0.f};
#pragma unroll
        for (int kk = 0; kk < 2; ++kk) {
            bf16x8 af[2], bfr[4];
#pragma unroll
            for (int i = 0; i < 2; ++i) af[i] = *(const bf16x8*)&Qs[(w * 32 + i * 16 + c) * 64 + kk * 32 + qd * 8];
#pragma unroll
            for (int j = 0; j < 4; ++j) bfr[j] = *(const bf16x8*)&Ks[(j * 16 + c) * 64 + kk * 32 + qd * 8];
#pragma unroll
            for (int i = 0; i < 2; ++i)
#pragma unroll
                for (int j = 0; j < 4; ++j)
                    sc_[i][j] = __builtin_amdgcn_mfma_f32_16x16x32_bf16(af[i], bfr[j], sc_[i][j], 0, 0, 0);
        }
        // online softmax, P -> LDS (bf16, A-operand friendly [q][s] row-major)
#pragma unroll
        for (int i = 0; i < 2; ++i)
#pragma unroll
            for (int r = 0; r < 4; ++r) {
                float mx = sc_[i][0][r];
#pragma unroll
                for (int j = 1; j < 4; ++j) mx = fmaxf(mx, sc_[i][j][r]);
                mx = rmax16(mx);
                float mnew = fmaxf(m_st[i][r], mx);
                float alpha = __expf(m_st[i][r] - mnew);
                float rs = 0.f;
#pragma unroll
                for (int j = 0; j < 4; ++j) {
                    float p = __expf(sc_[i][j][r] - mnew);
                    rs += p;
                    Ps[w][(i * 16 + qd * 4 + r) * 64 + j * 16 + c] = (bf16_t)p;
                }
                rs = rsum16(rs);
                l_st[i][r] = l_st[i][r] * alpha + rs;
                m_st[i][r] = mnew;
#pragma unroll
                for (int j = 0; j < 4; ++j) acc_o[i][j][r] *= alpha;
            }
        // O += P . V   (A = P from LDS, B = Vt tile)
#pragma unroll
        for (int kk = 0; kk < 2; ++kk) {
            bf16x8 pf[2], vf[4];
#pragma unroll
            for (int i = 0; i < 2; ++i) pf[i] = *(const bf16x8*)&Ps[w][(i * 16 + c) * 64 + kk * 32 + qd * 8];
#pragma unroll
            for (int j = 0; j < 4; ++j) vf[j] = *(const bf16x8*)&Vts[(j * 16 + c) * 64 + kk * 32 + qd * 8];
#pragma unroll
            for (int i = 0; i < 2; ++i)
#pragma unroll
                for (int j = 0; j < 4; ++j)
                    acc_o[i][j] = __builtin_amdgcn_mfma_f32_16x16x32_bf16(pf[i], vf[j], acc_o[i][j], 0, 0, 0);
        }
        __syncthreads();
    }
    const int b = bh >> 4, h = bh & 15;
#pragma unroll
    for (int i = 0; i < 2; ++i)
#pragma unroll
        for (int j = 0; j < 4; ++j)
#pragma unroll
            for (int r = 0; r < 4; ++r) {
                int qrow = q0 + w * 32 + i * 16 + qd * 4 + r;
                float o = acc_o[i][j][r] / l_st[i][r];
                ctx[((size_t)(b * 2048 + qrow)) * 1024 + (size_t)h * 64 + j * 16 + c] = (bf16_t)o;
            }
}

extern "C" void kernel_launch(void* const* d_in, const int* in_sizes, int n_in,
                              void* d_out, int out_size, void* d_ws, size_t ws_size,
                              hipStream_t stream) {
    (void)in_sizes; (void)n_in; (void)out_size; (void)ws_size;
    const float* query = (const float*)d_in[0];
    const float* key   = (const float*)d_in[1];
    const float* value = (const float*)d_in[2];
    const float* Wq = (const float*)d_in[3];
    const float* bq = (const float*)d_in[4];
    const float* Wk = (const float*)d_in[5];
    const float* bk = (const float*)d_in[6];
    const float* Wv = (const float*)d_in[7];
    const float* bv = (const float*)d_in[8];
    const float* Wo = (const float*)d_in[9];
    const float* bo = (const float*)d_in[10];

    const size_t SZ = (size_t)8192 * 1024;
    bf16_t* Xq = (bf16_t*)d_ws;
    bf16_t* Xk = Xq + SZ;
    bf16_t* Xv = Xk + SZ;
    bf16_t* Qb = Xv + SZ;
    bf16_t* Kb = Qb + SZ;
    bf16_t* Vb = Kb + SZ;
    bf16_t* Wqt = Vb + SZ;
    bf16_t* Wkt = Wqt + 1024 * 1024;
    bf16_t* Wvt = Wkt + 1024 * 1024;
    bf16_t* Wot = Wvt + 1024 * 1024;
    float* ctab = (float*)(Wot + 1024 * 1024);
    float* stab = ctab + 2048 * 32;
    bf16_t* Vtb = Xk;  // alias: Xk dead after K projection GEMM
    bf16_t* CT  = Xq;  // alias: Xq dead after Q projection GEMM

    castk<<<8192, 256, 0, stream>>>(query, Xq);
    castk<<<8192, 256, 0, stream>>>(key, Xk);
    castk<<<8192, 256, 0, stream>>>(value, Xv);
    wtrans<<<dim3(32, 32, 4), 256, 0, stream>>>(Wq, Wk, Wv, Wo, Wqt, Wkt, Wvt, Wot);
    rope_tab<<<256, 256, 0, stream>>>(ctab, stab);
    // Q: rope + fold 1/sqrt(hd)=0.125 into Q
    gemm_bt<0><<<dim3(8, 64), 256, 0, stream>>>(Xq, Wqt, bq, Qb, ctab, stab, 0.125f);
    gemm_bt<0><<<dim3(8, 64), 256, 0, stream>>>(Xk, Wkt, bk, Kb, ctab, stab, 1.0f);
    gemm_bt<1><<<dim3(8, 64), 256, 0, stream>>>(Xv, Wvt, bv, Vb, nullptr, nullptr, 1.0f);
    vtrans<<<dim3(32, 64), 256, 0, stream>>>(Vb, Vtb);
    attn<<<dim3(16, 64), 256, 0, stream>>>(Qb, Kb, Vtb, CT);
    gemm_bt<2><<<dim3(8, 64), 256, 0, stream>>>(CT, Wot, bo, d_out, nullptr, nullptr, 1.0f);
}

// Round 2
// 404.261 us; speedup vs baseline: 1.4107x; 1.4107x over previous
//
#include <hip/hip_runtime.h>
#include <hip/hip_bf16.h>
#include <cstdint>
#include <cstddef>

typedef __bf16 bf16_t;
typedef __bf16 bf16x8 __attribute__((ext_vector_type(8)));
typedef __bf16 bf16x4v __attribute__((ext_vector_type(4)));
typedef float f32x4 __attribute__((ext_vector_type(4)));

#define DEVI static __device__ __forceinline__

// async global->LDS, 16B per lane. LDS dest must be wave-uniform base + lane*16.
DEVI void gl_lds16(const void* g, void* l) {
    __builtin_amdgcn_global_load_lds((const __attribute__((address_space(1))) void*)g,
                                     (__attribute__((address_space(3))) void*)l, 16, 0, 0);
}

DEVI float rsum16(float v) {
    v += __shfl_xor(v, 1);
    v += __shfl_xor(v, 2);
    v += __shfl_xor(v, 4);
    v += __shfl_xor(v, 8);
    return v;
}

DEVI float fexp2(float x) {
#if __has_builtin(__builtin_amdgcn_exp2f)
    return __builtin_amdgcn_exp2f(x);
#else
    return __expf(x * 0.6931471805599453f);
#endif
}

// ---------------- cast fp32 -> bf16 (vectorized) ----------------
__global__ __launch_bounds__(256) void castk(const float* __restrict__ in, bf16_t* __restrict__ out) {
    size_t i = ((size_t)blockIdx.x * 256 + threadIdx.x) * 4;
    float4 v = *(const float4*)(in + i);
    bf16x4v o;
    o[0] = (bf16_t)v.x; o[1] = (bf16_t)v.y; o[2] = (bf16_t)v.z; o[3] = (bf16_t)v.w;
    *(bf16x4v*)(out + i) = o;
}

// ---------------- transpose+cast weight 1024x1024: Wt[n][k] = W[k][n] ----------------
__global__ __launch_bounds__(256) void wtrans(const float* __restrict__ W0, const float* __restrict__ W1,
                                              const float* __restrict__ W2, const float* __restrict__ W3,
                                              bf16_t* __restrict__ O0, bf16_t* __restrict__ O1,
                                              bf16_t* __restrict__ O2, bf16_t* __restrict__ O3) {
    const float* W; bf16_t* O;
    switch (blockIdx.z) {
        case 0: W = W0; O = O0; break;
        case 1: W = W1; O = O1; break;
        case 2: W = W2; O = O2; break;
        default: W = W3; O = O3; break;
    }
    __shared__ float t[32][33];
    int tx = threadIdx.x & 31, ty = threadIdx.x >> 5;   // 32x8
    int bx = blockIdx.x * 32, by = blockIdx.y * 32;     // bx: n, by: k
#pragma unroll
    for (int yy = 0; yy < 4; ++yy)
        t[ty + yy * 8][tx] = W[(size_t)(by + ty + yy * 8) * 1024 + bx + tx];
    __syncthreads();
#pragma unroll
    for (int yy = 0; yy < 4; ++yy)
        O[(size_t)(bx + ty + yy * 8) * 1024 + by + tx] = (bf16_t)t[tx][ty + yy * 8];
}

// ---------------- RoPE tables: ctab/stab [2048][32] fp32 ----------------
__global__ __launch_bounds__(256) void rope_tab(float* __restrict__ ctab, float* __restrict__ stab) {
    int idx = blockIdx.x * 256 + threadIdx.x;   // 65536 = 2048*32
    int s = idx >> 5, i = idx & 31;
    float inv = 1.0f / powf(10000.0f, (float)i * (1.0f / 32.0f));
    float f = (float)s * inv;
    ctab[idx] = cosf(f);
    stab[idx] = sinf(f);
}

// ---------------- GEMM: C[8192,1024] = A[8192,1024] x Bt[1024,1024]^T ----------------
// MODE 0: bf16 store to [b,h,s,d] with RoPE + scale (Q/K)
// MODE 2: fp32 store to [m,n] + bias (final out)
// MODE 3: bf16 store transposed to Vt[b,h,d,s] (V)
template <int MODE>
__global__ __launch_bounds__(256) void gemm_bt(const bf16_t* __restrict__ A, const bf16_t* __restrict__ Bt,
                                               const float* __restrict__ bias, void* __restrict__ Cout,
                                               const float* __restrict__ ctab, const float* __restrict__ stab,
                                               float scale) {
    constexpr int K = 1024, N = 1024;
    __shared__ alignas(16) bf16_t As[128 * 32];
    __shared__ alignas(16) bf16_t Bs[128 * 32];
    const int tid = threadIdx.x;
    const int w = tid >> 6, lane = tid & 63, c = lane & 15, qd = lane >> 4;
    const int wm = w >> 1, wn = w & 1;
    const int m0 = blockIdx.y * 128, n0 = blockIdx.x * 128;
    f32x4 acc[4][4] = {};
    for (int kt = 0; kt < K / 32; ++kt) {
#pragma unroll
        for (int l = 0; l < 2; ++l) {
            int e = (l * 256 + tid) * 8;
            int row = e >> 5, col = e & 31;
            gl_lds16(A + (size_t)(m0 + row) * K + kt * 32 + col, (char*)As + (size_t)e * 2);
            gl_lds16(Bt + (size_t)(n0 + row) * K + kt * 32 + col, (char*)Bs + (size_t)e * 2);
        }
        __syncthreads();
        bf16x8 af[4], bfr[4];
#pragma unroll
        for (int i = 0; i < 4; ++i) af[i] = *(const bf16x8*)&As[(wm * 64 + i * 16 + c) * 32 + qd * 8];
#pragma unroll
        for (int j = 0; j < 4; ++j) bfr[j] = *(const bf16x8*)&Bs[(wn * 64 + j * 16 + c) * 32 + qd * 8];
#pragma unroll
        for (int i = 0; i < 4; ++i)
#pragma unroll
            for (int j = 0; j < 4; ++j)
                acc[i][j] = __builtin_amdgcn_mfma_f32_16x16x32_bf16(af[i], bfr[j], acc[i][j], 0, 0, 0);
        __syncthreads();
    }
    const int mb = m0 + wm * 64;
    const int nb = n0 + wn * 64;   // head-aligned (64): nb>>6 = head for MODE 0/3
    if constexpr (MODE == 2) {
        float* O = (float*)Cout;
#pragma unroll
        for (int i = 0; i < 4; ++i)
#pragma unroll
            for (int j = 0; j < 4; ++j) {
                int n = nb + j * 16 + c;
                float bv = bias[n];
#pragma unroll
                for (int r = 0; r < 4; ++r) {
                    int m = mb + i * 16 + qd * 4 + r;
                    O[(size_t)m * N + n] = acc[i][j][r] + bv;
                }
            }
    } else if constexpr (MODE == 3) {
        // V: store transposed Vt[b,h,d,s], packing 4 consecutive s per store
        bf16_t* O = (bf16_t*)Cout;
        int h = nb >> 6;
#pragma unroll
        for (int i = 0; i < 4; ++i) {
            int m = mb + i * 16 + qd * 4;     // 4 consecutive s at r=0..3, same b
            int b = m >> 11, s = m & 2047;
#pragma unroll
            for (int j = 0; j < 4; ++j) {
                int d = j * 16 + c;
                float bv = bias[nb + d];
                bf16x4v v4;
#pragma unroll
                for (int r = 0; r < 4; ++r) v4[r] = (bf16_t)(acc[i][j][r] + bv);
                *(bf16x4v*)((bf16_t*)O + ((size_t)(b * 16 + h) * 64 + d) * 2048 + s) = v4;
            }
        }
    } else {
        bf16_t* O = (bf16_t*)Cout;
        int h = nb >> 6;
#pragma unroll
        for (int i = 0; i < 4; ++i)
#pragma unroll
            for (int jh = 0; jh < 2; ++jh) {
                int d1 = jh * 16 + c;                 // [0,32)
                float b1 = bias[nb + d1];
                float b2 = bias[nb + d1 + 32];
#pragma unroll
                for (int r = 0; r < 4; ++r) {
                    int m = mb + i * 16 + qd * 4 + r;
                    int b = m >> 11, s = m & 2047;
                    float v1 = acc[i][jh][r] + b1;
                    float v2 = acc[i][jh + 2][r] + b2;
                    float ct = ctab[s * 32 + d1];
                    float st = stab[s * 32 + d1];
                    size_t base = ((size_t)(b * 16 + h) * 2048 + s) * 64;
                    O[base + d1]      = (bf16_t)((v1 * ct - v2 * st) * scale);
                    O[base + d1 + 32] = (bf16_t)((v2 * ct + v1 * st) * scale);
                }
            }
    }
}

// ---------------- flash attention v2: swizzled LDS, max-free softmax ----------------
// Q pre-scaled by log2(e)/8 (exp2 path). Q,K: [b,h,s,64] bf16. Vt: [b,h,64,s] bf16.
// All LDS tiles: 64-bf16 rows, 16B-chunk XOR swizzle chunk' = chunk ^ ((row>>1)&7):
//   - conflict-free b128 fragment reads (8 words/bank = minimum)
//   - conflict-free scalar bf16 P-writes (2 lanes/bank = free)
// Staging permutes the GLOBAL source chunk (gl_lds LDS dest must stay lane-contiguous).
__global__ __launch_bounds__(256) void attn(const bf16_t* __restrict__ Q, const bf16_t* __restrict__ K,
                                            const bf16_t* __restrict__ Vt, bf16_t* __restrict__ ctx) {
    constexpr int S = 2048;
    __shared__ alignas(16) bf16_t Qs[128 * 64];
    __shared__ alignas(16) bf16_t Ks[64 * 64];
    __shared__ alignas(16) bf16_t Vts[64 * 64];
    __shared__ alignas(16) bf16_t Ps[4][32 * 64];
    const int tid = threadIdx.x, w = tid >> 6, lane = tid & 63, c = lane & 15, qd = lane >> 4;
    const int bh = blockIdx.y, q0 = blockIdx.x * 128;
    const bf16_t* Qb = Q + (size_t)bh * S * 64 + (size_t)q0 * 64;
    const bf16_t* Kb = K + (size_t)bh * S * 64;
    const bf16_t* Vb = Vt + (size_t)bh * 64 * S;
#pragma unroll
    for (int l = 0; l < 4; ++l) {
        int slot = l * 256 + tid;           // 16B slots
        int row = slot >> 3, ch = slot & 7;
        int sch = ch ^ ((row >> 1) & 7);
        gl_lds16(Qb + (size_t)row * 64 + sch * 8, (char*)Qs + (size_t)slot * 16);
    }
    f32x4 acc_o[2][4] = {};
    float l_st[2][4] = {};
    const int rch = (c >> 1) & 7;           // read-side swizzle mask (row = ...16*x + c)
    __syncthreads();
    for (int kt = 0; kt < S / 64; ++kt) {
        const int s0 = kt * 64;
#pragma unroll
        for (int l = 0; l < 2; ++l) {
            int slot = l * 256 + tid;
            int row = slot >> 3, ch = slot & 7;
            int sch = ch ^ ((row >> 1) & 7);
            gl_lds16(Kb + (size_t)(s0 + row) * 64 + sch * 8, (char*)Ks + (size_t)slot * 16);
            gl_lds16(Vb + (size_t)row * S + s0 + sch * 8, (char*)Vts + (size_t)slot * 16);
        }
        __syncthreads();
        // S_tile = Q . K^T  (scores pre-scaled by log2e/8 via Q)
        f32x4 sc[2][4] = {};
#pragma unroll
        for (int kk = 0; kk < 2; ++kk) {
            const int ch = (4 * kk + qd) ^ rch;
            bf16x8 af[2], bfr[4];
#pragma unroll
            for (int i = 0; i < 2; ++i) af[i] = *(const bf16x8*)&Qs[(w * 32 + i * 16 + c) * 64 + ch * 8];
#pragma unroll
            for (int j = 0; j < 4; ++j) bfr[j] = *(const bf16x8*)&Ks[(j * 16 + c) * 64 + ch * 8];
#pragma unroll
            for (int i = 0; i < 2; ++i)
#pragma unroll
                for (int j = 0; j < 4; ++j)
                    sc[i][j] = __builtin_amdgcn_mfma_f32_16x16x32_bf16(af[i], bfr[j], sc[i][j], 0, 0, 0);
        }
        // max-free softmax: p = 2^sc, row-sum accumulated in registers, P -> LDS swizzled
#pragma unroll
        for (int i = 0; i < 2; ++i)
#pragma unroll
            for (int r = 0; r < 4; ++r) {
                int rowp = i * 16 + qd * 4 + r;
                int msk = (rowp >> 1) & 7;
                float rs = 0.f;
#pragma unroll
                for (int j = 0; j < 4; ++j) {
                    float p = fexp2(sc[i][j][r]);
                    rs += p;
                    int ch = (2 * j + (c >> 3)) ^ msk;
                    Ps[w][rowp * 64 + ch * 8 + (c & 7)] = (bf16_t)p;
                }
                l_st[i][r] += rs;
            }
        // O += P . V
#pragma unroll
        for (int kk = 0; kk < 2; ++kk) {
            const int ch = (4 * kk + qd) ^ rch;
            bf16x8 pf[2], vf[4];
#pragma unroll
            for (int i = 0; i < 2; ++i) pf[i] = *(const bf16x8*)&Ps[w][(i * 16 + c) * 64 + ch * 8];
#pragma unroll
            for (int j = 0; j < 4; ++j) vf[j] = *(const bf16x8*)&Vts[(j * 16 + c) * 64 + ch * 8];
#pragma unroll
            for (int i = 0; i < 2; ++i)
#pragma unroll
                for (int j = 0; j < 4; ++j)
                    acc_o[i][j] = __builtin_amdgcn_mfma_f32_16x16x32_bf16(pf[i], vf[j], acc_o[i][j], 0, 0, 0);
        }
        __syncthreads();
    }
    // single end-of-row reduction of l across the 16 c-lanes
    float linv[2][4];
#pragma unroll
    for (int i = 0; i < 2; ++i)
#pragma unroll
        for (int r = 0; r < 4; ++r) linv[i][r] = 1.0f / rsum16(l_st[i][r]);
    const int b = bh >> 4, h = bh & 15;
#pragma unroll
    for (int i = 0; i < 2; ++i)
#pragma unroll
        for (int j = 0; j < 4; ++j)
#pragma unroll
            for (int r = 0; r < 4; ++r) {
                int qrow = q0 + w * 32 + i * 16 + qd * 4 + r;
                float o = acc_o[i][j][r] * linv[i][r];
                ctx[((size_t)(b * 2048 + qrow)) * 1024 + (size_t)h * 64 + j * 16 + c] = (bf16_t)o;
            }
}

extern "C" void kernel_launch(void* const* d_in, const int* in_sizes, int n_in,
                              void* d_out, int out_size, void* d_ws, size_t ws_size,
                              hipStream_t stream) {
    (void)in_sizes; (void)n_in; (void)out_size; (void)ws_size;
    const float* query = (const float*)d_in[0];
    const float* key   = (const float*)d_in[1];
    const float* value = (const float*)d_in[2];
    const float* Wq = (const float*)d_in[3];
    const float* bq = (const float*)d_in[4];
    const float* Wk = (const float*)d_in[5];
    const float* bk = (const float*)d_in[6];
    const float* Wv = (const float*)d_in[7];
    const float* bv = (const float*)d_in[8];
    const float* Wo = (const float*)d_in[9];
    const float* bo = (const float*)d_in[10];

    const size_t SZ = (size_t)8192 * 1024;
    bf16_t* Xq = (bf16_t*)d_ws;
    bf16_t* Xk = Xq + SZ;
    bf16_t* Xv = Xk + SZ;
    bf16_t* Qb = Xv + SZ;
    bf16_t* Kb = Qb + SZ;
    bf16_t* spare = Kb + SZ;   // 16MB unused (was Vb)
    bf16_t* Wqt = spare + SZ;
    bf16_t* Wkt = Wqt + 1024 * 1024;
    bf16_t* Wvt = Wkt + 1024 * 1024;
    bf16_t* Wot = Wvt + 1024 * 1024;
    float* ctab = (float*)(Wot + 1024 * 1024);
    float* stab = ctab + 2048 * 32;
    bf16_t* Vtb = Xk;  // alias: Xk dead after K projection GEMM
    bf16_t* CT  = Xq;  // alias: Xq dead after Q projection GEMM

    castk<<<8192, 256, 0, stream>>>(query, Xq);
    castk<<<8192, 256, 0, stream>>>(key, Xk);
    castk<<<8192, 256, 0, stream>>>(value, Xv);
    wtrans<<<dim3(32, 32, 4), 256, 0, stream>>>(Wq, Wk, Wv, Wo, Wqt, Wkt, Wvt, Wot);
    rope_tab<<<256, 256, 0, stream>>>(ctab, stab);
    // Q: rope + fold (1/sqrt(hd)) * log2(e) = 0.125 * 1.4426950408889634 into Q
    gemm_bt<0><<<dim3(8, 64), 256, 0, stream>>>(Xq, Wqt, bq, Qb, ctab, stab, 0.18033688011112042f);
    gemm_bt<0><<<dim3(8, 64), 256, 0, stream>>>(Xk, Wkt, bk, Kb, ctab, stab, 1.0f);
    gemm_bt<3><<<dim3(8, 64), 256, 0, stream>>>(Xv, Wvt, bv, Vtb, nullptr, nullptr, 1.0f);
    attn<<<dim3(16, 64), 256, 0, stream>>>(Qb, Kb, Vtb, CT);
    gemm_bt<2><<<dim3(8, 64), 256, 0, stream>>>(CT, Wot, bo, d_out, nullptr, nullptr, 1.0f);
}

// Round 3
// 387.229 us; speedup vs baseline: 1.4728x; 1.0440x over previous
//
#include <hip/hip_runtime.h>
#include <hip/hip_bf16.h>
#include <cstdint>
#include <cstddef>

typedef __bf16 bf16_t;
typedef __bf16 bf16x8 __attribute__((ext_vector_type(8)));
typedef __bf16 bf16x4v __attribute__((ext_vector_type(4)));
typedef __bf16 bf16x2v __attribute__((ext_vector_type(2)));
typedef float f32x4 __attribute__((ext_vector_type(4)));
typedef uint32_t u32x4 __attribute__((ext_vector_type(4)));

#define DEVI static __device__ __forceinline__

// async global->LDS, 16B per lane. LDS dest must be wave-uniform base + lane*16.
DEVI void gl_lds16(const void* g, void* l) {
    __builtin_amdgcn_global_load_lds((const __attribute__((address_space(1))) void*)g,
                                     (__attribute__((address_space(3))) void*)l, 16, 0, 0);
}

DEVI float fexp2(float x) {
#if __has_builtin(__builtin_amdgcn_exp2f)
    return __builtin_amdgcn_exp2f(x);
#else
    return __expf(x * 0.6931471805599453f);
#endif
}

DEVI uint32_t pkbf16(float a, float b) {
    bf16x2v t;
    t[0] = (bf16_t)a;
    t[1] = (bf16_t)b;
    return __builtin_bit_cast(uint32_t, t);
}

// ---------------- cast fp32 -> bf16 (3 tensors in one launch) ----------------
__global__ __launch_bounds__(256) void castk(const float* __restrict__ i0, const float* __restrict__ i1,
                                             const float* __restrict__ i2, bf16_t* __restrict__ o0,
                                             bf16_t* __restrict__ o1, bf16_t* __restrict__ o2) {
    const float* in = blockIdx.y == 0 ? i0 : blockIdx.y == 1 ? i1 : i2;
    bf16_t* out = blockIdx.y == 0 ? o0 : blockIdx.y == 1 ? o1 : o2;
    size_t i = ((size_t)blockIdx.x * 256 + threadIdx.x) * 4;
    float4 v = *(const float4*)(in + i);
    bf16x4v o;
    o[0] = (bf16_t)v.x; o[1] = (bf16_t)v.y; o[2] = (bf16_t)v.z; o[3] = (bf16_t)v.w;
    *(bf16x4v*)(out + i) = o;
}

// ---------------- transpose+cast weight 1024x1024: Wt[n][k] = W[k][n] ----------------
__global__ __launch_bounds__(256) void wtrans(const float* __restrict__ W0, const float* __restrict__ W1,
                                              const float* __restrict__ W2, const float* __restrict__ W3,
                                              bf16_t* __restrict__ O0, bf16_t* __restrict__ O1,
                                              bf16_t* __restrict__ O2, bf16_t* __restrict__ O3) {
    const float* W; bf16_t* O;
    switch (blockIdx.z) {
        case 0: W = W0; O = O0; break;
        case 1: W = W1; O = O1; break;
        case 2: W = W2; O = O2; break;
        default: W = W3; O = O3; break;
    }
    __shared__ float t[32][33];
    int tx = threadIdx.x & 31, ty = threadIdx.x >> 5;   // 32x8
    int bx = blockIdx.x * 32, by = blockIdx.y * 32;     // bx: n, by: k
#pragma unroll
    for (int yy = 0; yy < 4; ++yy)
        t[ty + yy * 8][tx] = W[(size_t)(by + ty + yy * 8) * 1024 + bx + tx];
    __syncthreads();
#pragma unroll
    for (int yy = 0; yy < 4; ++yy)
        O[(size_t)(bx + ty + yy * 8) * 1024 + by + tx] = (bf16_t)t[tx][ty + yy * 8];
}

// ---------------- RoPE tables: ctab/stab [2048][32] fp32 ----------------
__global__ __launch_bounds__(256) void rope_tab(float* __restrict__ ctab, float* __restrict__ stab) {
    int idx = blockIdx.x * 256 + threadIdx.x;   // 65536 = 2048*32
    int s = idx >> 5, i = idx & 31;
    float inv = 1.0f / powf(10000.0f, (float)i * (1.0f / 32.0f));
    float f = (float)s * inv;
    ctab[idx] = cosf(f);
    stab[idx] = sinf(f);
}

// ---------------- fused QKV projection GEMM (grid.z selects Q/K/V) ----------------
// C[8192,1024] = A[8192,1024] x Wt[1024,1024]^T; epilogue:
//   z=0/1: RoPE + scale, bf16 store to [b,h,s,d]    (Q: scale=log2e/8, K: scale=1)
//   z=2:   bf16 store transposed to Vt[b,h,d,s]
__global__ __launch_bounds__(256) void gemm_qkv(const bf16_t* __restrict__ Xq, const bf16_t* __restrict__ Xk,
                                                const bf16_t* __restrict__ Xv, const bf16_t* __restrict__ Wqt,
                                                const bf16_t* __restrict__ Wkt, const bf16_t* __restrict__ Wvt,
                                                const float* __restrict__ bqp, const float* __restrict__ bkp,
                                                const float* __restrict__ bvp, bf16_t* __restrict__ Qo,
                                                bf16_t* __restrict__ Ko, bf16_t* __restrict__ Vo,
                                                const float* __restrict__ ctab, const float* __restrict__ stab) {
    constexpr int K = 1024;
    const int z = blockIdx.z;
    const bf16_t* A  = z == 0 ? Xq : z == 1 ? Xk : Xv;
    const bf16_t* Bt = z == 0 ? Wqt : z == 1 ? Wkt : Wvt;
    const float* bias = z == 0 ? bqp : z == 1 ? bkp : bvp;
    bf16_t* O = z == 0 ? Qo : z == 1 ? Ko : Vo;
    const float scale = z == 0 ? 0.18033688011112042f : 1.0f;   // log2(e)/8 folded into Q

    __shared__ alignas(16) bf16_t As[128 * 32];
    __shared__ alignas(16) bf16_t Bs[128 * 32];
    const int tid = threadIdx.x;
    const int w = tid >> 6, lane = tid & 63, c = lane & 15, qd = lane >> 4;
    const int wm = w >> 1, wn = w & 1;
    const int m0 = blockIdx.y * 128, n0 = blockIdx.x * 128;
    f32x4 acc[4][4] = {};
    for (int kt = 0; kt < K / 32; ++kt) {
#pragma unroll
        for (int l = 0; l < 2; ++l) {
            int e = (l * 256 + tid) * 8;
            int row = e >> 5, col = e & 31;
            gl_lds16(A + (size_t)(m0 + row) * K + kt * 32 + col, (char*)As + (size_t)e * 2);
            gl_lds16(Bt + (size_t)(n0 + row) * K + kt * 32 + col, (char*)Bs + (size_t)e * 2);
        }
        __syncthreads();
        bf16x8 af[4], bfr[4];
#pragma unroll
        for (int i = 0; i < 4; ++i) af[i] = *(const bf16x8*)&As[(wm * 64 + i * 16 + c) * 32 + qd * 8];
#pragma unroll
        for (int j = 0; j < 4; ++j) bfr[j] = *(const bf16x8*)&Bs[(wn * 64 + j * 16 + c) * 32 + qd * 8];
#pragma unroll
        for (int i = 0; i < 4; ++i)
#pragma unroll
            for (int j = 0; j < 4; ++j)
                acc[i][j] = __builtin_amdgcn_mfma_f32_16x16x32_bf16(af[i], bfr[j], acc[i][j], 0, 0, 0);
        __syncthreads();
    }
    const int mb = m0 + wm * 64;
    const int nb = n0 + wn * 64;   // head-aligned (64): nb>>6 = head
    const int h = nb >> 6;
    if (z == 2) {
        // V: store transposed Vt[b,h,d,s], packing 4 consecutive s per store
#pragma unroll
        for (int i = 0; i < 4; ++i) {
            int m = mb + i * 16 + qd * 4;     // 4 consecutive s at r=0..3, same b
            int b = m >> 11, s = m & 2047;
#pragma unroll
            for (int j = 0; j < 4; ++j) {
                int d = j * 16 + c;
                float bv = bias[nb + d];
                bf16x4v v4;
#pragma unroll
                for (int r = 0; r < 4; ++r) v4[r] = (bf16_t)(acc[i][j][r] + bv);
                *(bf16x4v*)(O + ((size_t)(b * 16 + h) * 64 + d) * 2048 + s) = v4;
            }
        }
    } else {
#pragma unroll
        for (int i = 0; i < 4; ++i)
#pragma unroll
            for (int jh = 0; jh < 2; ++jh) {
                int d1 = jh * 16 + c;                 // [0,32)
                float b1 = bias[nb + d1];
                float b2 = bias[nb + d1 + 32];
#pragma unroll
                for (int r = 0; r < 4; ++r) {
                    int m = mb + i * 16 + qd * 4 + r;
                    int b = m >> 11, s = m & 2047;
                    float v1 = acc[i][jh][r] + b1;
                    float v2 = acc[i][jh + 2][r] + b2;
                    float ct = ctab[s * 32 + d1];
                    float st = stab[s * 32 + d1];
                    size_t base = ((size_t)(b * 16 + h) * 2048 + s) * 64;
                    O[base + d1]      = (bf16_t)((v1 * ct - v2 * st) * scale);
                    O[base + d1 + 32] = (bf16_t)((v2 * ct + v1 * st) * scale);
                }
            }
    }
}

// ---------------- GEMM MODE 2: fp32 store [m,n] + bias (final out-proj) ----------------
__global__ __launch_bounds__(256) void gemm_out(const bf16_t* __restrict__ A, const bf16_t* __restrict__ Bt,
                                                const float* __restrict__ bias, float* __restrict__ O) {
    constexpr int K = 1024, N = 1024;
    __shared__ alignas(16) bf16_t As[128 * 32];
    __shared__ alignas(16) bf16_t Bs[128 * 32];
    const int tid = threadIdx.x;
    const int w = tid >> 6, lane = tid & 63, c = lane & 15, qd = lane >> 4;
    const int wm = w >> 1, wn = w & 1;
    const int m0 = blockIdx.y * 128, n0 = blockIdx.x * 128;
    f32x4 acc[4][4] = {};
    for (int kt = 0; kt < K / 32; ++kt) {
#pragma unroll
        for (int l = 0; l < 2; ++l) {
            int e = (l * 256 + tid) * 8;
            int row = e >> 5, col = e & 31;
            gl_lds16(A + (size_t)(m0 + row) * K + kt * 32 + col, (char*)As + (size_t)e * 2);
            gl_lds16(Bt + (size_t)(n0 + row) * K + kt * 32 + col, (char*)Bs + (size_t)e * 2);
        }
        __syncthreads();
        bf16x8 af[4], bfr[4];
#pragma unroll
        for (int i = 0; i < 4; ++i) af[i] = *(const bf16x8*)&As[(wm * 64 + i * 16 + c) * 32 + qd * 8];
#pragma unroll
        for (int j = 0; j < 4; ++j) bfr[j] = *(const bf16x8*)&Bs[(wn * 64 + j * 16 + c) * 32 + qd * 8];
#pragma unroll
        for (int i = 0; i < 4; ++i)
#pragma unroll
            for (int j = 0; j < 4; ++j)
                acc[i][j] = __builtin_amdgcn_mfma_f32_16x16x32_bf16(af[i], bfr[j], acc[i][j], 0, 0, 0);
        __syncthreads();
    }
    const int mb = m0 + wm * 64, nb = n0 + wn * 64;
#pragma unroll
    for (int i = 0; i < 4; ++i)
#pragma unroll
        for (int j = 0; j < 4; ++j) {
            int n = nb + j * 16 + c;
            float bv = bias[n];
#pragma unroll
            for (int r = 0; r < 4; ++r) {
                int m = mb + i * 16 + qd * 4 + r;
                O[(size_t)m * N + n] = acc[i][j][r] + bv;
            }
        }
}

// ---------------- flash attention v3 ----------------
// Swapped-QK (St = K.Q^T) so P exits MFMA with 4 consecutive s per lane; exp2 + pack to
// bf16 pairs in-register; PV A-frags assembled via 8 shfl + 4 selects each (no P LDS).
// Double-buffered K/V staging: one barrier per tile, prefetch overlaps full compute phase.
// Q fragments hoisted to registers (tile-invariant). LDS 48KB -> 3 blocks/CU.
// Q pre-scaled by log2(e)/8. Q,K: [b,h,s,64] bf16. Vt: [b,h,64,s] bf16.
// 16B-chunk XOR swizzle (chunk^((row>>1)&7)) keeps all b128 reads conflict-free.
__global__ __launch_bounds__(256, 3) void attn(const bf16_t* __restrict__ Q, const bf16_t* __restrict__ K,
                                               const bf16_t* __restrict__ Vt, bf16_t* __restrict__ ctx) {
    constexpr int S = 2048;
    __shared__ alignas(16) bf16_t Qs[128 * 64];
    __shared__ alignas(16) bf16_t Ks[2][64 * 64];
    __shared__ alignas(16) bf16_t Vts[2][64 * 64];
    const int tid = threadIdx.x, w = tid >> 6, lane = tid & 63, c = lane & 15, qd = lane >> 4;
    const int bh = blockIdx.y, q0 = blockIdx.x * 128;
    const bf16_t* Qb = Q + (size_t)bh * S * 64 + (size_t)q0 * 64;
    const bf16_t* Kb = K + (size_t)bh * S * 64;
    const bf16_t* Vb = Vt + (size_t)bh * 64 * S;
#pragma unroll
    for (int l = 0; l < 4; ++l) {
        int slot = l * 256 + tid;           // 16B slots
        int row = slot >> 3, ch = slot & 7;
        int sch = ch ^ ((row >> 1) & 7);
        gl_lds16(Qb + (size_t)row * 64 + sch * 8, (char*)Qs + (size_t)slot * 16);
    }
    auto stageKV = [&](int kt, int buf) {
        const int s0 = kt * 64;
#pragma unroll
        for (int l = 0; l < 2; ++l) {
            int slot = l * 256 + tid;
            int row = slot >> 3, ch = slot & 7;
            int sch = ch ^ ((row >> 1) & 7);
            gl_lds16(Kb + (size_t)(s0 + row) * 64 + sch * 8, (char*)&Ks[buf][0] + (size_t)slot * 16);
            gl_lds16(Vb + (size_t)row * S + s0 + sch * 8, (char*)&Vts[buf][0] + (size_t)slot * 16);
        }
    };
    stageKV(0, 0);
    const int rch = (c >> 1) & 7;                   // read-side swizzle mask
    const int srcA = c + ((lane >> 4) & 1) * 32;    // (c, (qd&1)*2)
    const int srcB = srcA + 16;                     // (c, (qd&1)*2+1)
    const bool hisel = (qd >> 1) & 1;               // strip select: j = 2*kk + (qd>>1)
    f32x4 acc_o[2][4] = {};
    float ls[2] = {0.f, 0.f};
    const f32x4 Z = {0.f, 0.f, 0.f, 0.f};
    __syncthreads();
    // Q fragments (B-operand of swapped QK): tile-invariant, hoist to registers
    bf16x8 qf[2][2];
#pragma unroll
    for (int kk = 0; kk < 2; ++kk) {
        const int ch = (4 * kk + qd) ^ rch;
#pragma unroll
        for (int i = 0; i < 2; ++i)
            qf[kk][i] = *(const bf16x8*)&Qs[(w * 32 + i * 16 + c) * 64 + ch * 8];
    }
    for (int kt = 0; kt < S / 64; ++kt) {
        const int cur = kt & 1;
        if (kt + 1 < S / 64) stageKV(kt + 1, cur ^ 1);
        // St = K.Q^T : lane holds St[s=j*16+qd*4+r][q=i*16+c]
        f32x4 sc[4][2];
#pragma unroll
        for (int kk = 0; kk < 2; ++kk) {
            const int ch = (4 * kk + qd) ^ rch;
            bf16x8 kf[4];
#pragma unroll
            for (int j = 0; j < 4; ++j) kf[j] = *(const bf16x8*)&Ks[cur][(j * 16 + c) * 64 + ch * 8];
#pragma unroll
            for (int j = 0; j < 4; ++j)
#pragma unroll
                for (int i = 0; i < 2; ++i)
                    sc[j][i] = __builtin_amdgcn_mfma_f32_16x16x32_bf16(kf[j], qf[kk][i],
                                                                       kk == 0 ? Z : sc[j][i], 0, 0, 0);
        }
        // p = 2^sc; row-sum per q (lane's q = i*16+c); pack pairs (s, s+1) -> u32
        uint32_t pku[4][2][2];
#pragma unroll
        for (int j = 0; j < 4; ++j)
#pragma unroll
            for (int i = 0; i < 2; ++i) {
                float p0 = fexp2(sc[j][i][0]), p1 = fexp2(sc[j][i][1]);
                float p2 = fexp2(sc[j][i][2]), p3 = fexp2(sc[j][i][3]);
                ls[i] += (p0 + p1) + (p2 + p3);
                pku[j][i][0] = pkbf16(p0, p1);
                pku[j][i][1] = pkbf16(p2, p3);
            }
        // O += P.V : A-frag built cross-lane, B-frag from Vts rows (d-major)
#pragma unroll
        for (int kk = 0; kk < 2; ++kk) {
            const int ch = (4 * kk + qd) ^ rch;
            bf16x8 vf[4];
#pragma unroll
            for (int j = 0; j < 4; ++j) vf[j] = *(const bf16x8*)&Vts[cur][(j * 16 + c) * 64 + ch * 8];
#pragma unroll
            for (int i = 0; i < 2; ++i) {
                uint32_t a0, a1, a2, a3;
                {
                    uint32_t lo = __shfl(pku[2 * kk][i][0], srcA);
                    uint32_t hi = __shfl(pku[2 * kk + 1][i][0], srcA);
                    a0 = hisel ? hi : lo;
                    lo = __shfl(pku[2 * kk][i][1], srcA);
                    hi = __shfl(pku[2 * kk + 1][i][1], srcA);
                    a1 = hisel ? hi : lo;
                    lo = __shfl(pku[2 * kk][i][0], srcB);
                    hi = __shfl(pku[2 * kk + 1][i][0], srcB);
                    a2 = hisel ? hi : lo;
                    lo = __shfl(pku[2 * kk][i][1], srcB);
                    hi = __shfl(pku[2 * kk + 1][i][1], srcB);
                    a3 = hisel ? hi : lo;
                }
                u32x4 av = {a0, a1, a2, a3};
                bf16x8 af = __builtin_bit_cast(bf16x8, av);
#pragma unroll
                for (int j = 0; j < 4; ++j)
                    acc_o[i][j] = __builtin_amdgcn_mfma_f32_16x16x32_bf16(af, vf[j], acc_o[i][j], 0, 0, 0);
            }
        }
        __syncthreads();
    }
    // complete l over qd groups, redistribute inverse to C-layout rows
    float linv[2][4];
#pragma unroll
    for (int i = 0; i < 2; ++i) {
        float v = ls[i];
        v += __shfl_xor(v, 16);
        v += __shfl_xor(v, 32);
        float vinv = 1.0f / v;
#pragma unroll
        for (int r = 0; r < 4; ++r)
            linv[i][r] = __shfl(vinv, qd * 20 + r);   // lane (qd*16 + qd*4 + r): holds l[q=i*16+qd*4+r]
    }
    const int b = bh >> 4, h = bh & 15;
#pragma unroll
    for (int i = 0; i < 2; ++i)
#pragma unroll
        for (int j = 0; j < 4; ++j)
#pragma unroll
            for (int r = 0; r < 4; ++r) {
                int qrow = q0 + w * 32 + i * 16 + qd * 4 + r;
                float o = acc_o[i][j][r] * linv[i][r];
                ctx[((size_t)(b * 2048 + qrow)) * 1024 + (size_t)h * 64 + j * 16 + c] = (bf16_t)o;
            }
}

extern "C" void kernel_launch(void* const* d_in, const int* in_sizes, int n_in,
                              void* d_out, int out_size, void* d_ws, size_t ws_size,
                              hipStream_t stream) {
    (void)in_sizes; (void)n_in; (void)out_size; (void)ws_size;
    const float* query = (const float*)d_in[0];
    const float* key   = (const float*)d_in[1];
    const float* value = (const float*)d_in[2];
    const float* Wq = (const float*)d_in[3];
    const float* bq = (const float*)d_in[4];
    const float* Wk = (const float*)d_in[5];
    const float* bk = (const float*)d_in[6];
    const float* Wv = (const float*)d_in[7];
    const float* bv = (const float*)d_in[8];
    const float* Wo = (const float*)d_in[9];
    const float* bo = (const float*)d_in[10];

    const size_t SZ = (size_t)8192 * 1024;
    bf16_t* Xq = (bf16_t*)d_ws;
    bf16_t* Xk = Xq + SZ;
    bf16_t* Xv = Xk + SZ;
    bf16_t* Qb = Xv + SZ;
    bf16_t* Kb = Qb + SZ;
    bf16_t* Vtb = Kb + SZ;          // own buffer: fused QKV gemm runs Q/K/V concurrently
    bf16_t* Wqt = Vtb + SZ;
    bf16_t* Wkt = Wqt + 1024 * 1024;
    bf16_t* Wvt = Wkt + 1024 * 1024;
    bf16_t* Wot = Wvt + 1024 * 1024;
    float* ctab = (float*)(Wot + 1024 * 1024);
    float* stab = ctab + 2048 * 32;
    bf16_t* CT = Xq;                // alias: Xq dead after projection GEMM

    castk<<<dim3(8192, 3), 256, 0, stream>>>(query, key, value, Xq, Xk, Xv);
    wtrans<<<dim3(32, 32, 4), 256, 0, stream>>>(Wq, Wk, Wv, Wo, Wqt, Wkt, Wvt, Wot);
    rope_tab<<<256, 256, 0, stream>>>(ctab, stab);
    gemm_qkv<<<dim3(8, 64, 3), 256, 0, stream>>>(Xq, Xk, Xv, Wqt, Wkt, Wvt, bq, bk, bv,
                                                 Qb, Kb, Vtb, ctab, stab);
    attn<<<dim3(16, 64), 256, 0, stream>>>(Qb, Kb, Vtb, CT);
    gemm_out<<<dim3(8, 64), 256, 0, stream>>>(CT, Wot, bo, (float*)d_out);
}